// Round 11
// baseline (220.479 us; speedup 1.0000x reference)
//
#include <hip/hip_runtime.h>
#include <hip/hip_bf16.h>
#include <stdint.h>

typedef __attribute__((ext_vector_type(8))) short short8;
typedef __attribute__((ext_vector_type(4))) float f32x4;
typedef __attribute__((ext_vector_type(4))) int int4v;

__device__ __forceinline__ unsigned short f2bf(float f) {
    union { float f; uint32_t u; } v; v.f = f;
    return (unsigned short)((v.u + 0x7FFFu + ((v.u >> 16) & 1u)) >> 16);
}

// Build W directly in MFMA-FRAGMENT order:
//   Wfrag[((ct*6 + c)*64 + lane)*8 + e] = bf16( W[ct*16 + (lane&15)][c*32 + (lane>>4)*8 + e] )
// where W[j][k] = kernel[cayley[inv[k>>4], j>>4]][j&15][k&15].
// Each wave's ds_read_b128 for (ct,c) is lane-linear 16B -> conflict-free (R8/R9: 0 conflicts).
__global__ void build_w_kernel(const float* __restrict__ kern,
                               const int* __restrict__ cayley,
                               const int* __restrict__ inv,
                               unsigned short* __restrict__ Wfrag) {
    int i = blockIdx.x * blockDim.x + threadIdx.x;   // i = ((ct*6+c)*64 + lane)*8 + e
    if (i >= 192 * 192) return;
    int e    = i & 7;
    int lane = (i >> 3) & 63;
    int fc   = i >> 9;            // ct*6 + c
    int ct   = fc / 6, c = fc - ct * 6;
    int j = ct * 16 + (lane & 15);
    int k = c * 32 + (lane >> 4) * 8 + e;
    int h = j >> 4, oc = j & 15;
    int g = k >> 4, ic = k & 15;
    int cidx = cayley[inv[g] * 12 + h];
    Wfrag[i] = f2bf(kern[cidx * 256 + oc * 16 + ic]);
}

// out[n][j] = sum_k x[n][k] * W[j][k] + bias[j]
// R9 post-mortem: VGPR=60, zero spills, but LDS-capped at 2 blocks/CU x 8 waves
// = 16 waves/CU (Occ 32.6%). This round: 1024-thr blocks (16 waves) so the SAME
// 2-blocks/CU LDS footprint (2 x 73.7 KB = 147 <= 160 KB) carries 32 waves/CU.
// __launch_bounds__(1024,4) => 64-VGPR cap (ledger: cap = 256/arg2); R9 body
// compiled to 60 <= 64 so no spill expected. Keep R9's spill guards:
// two-batch staging + sched_barrier(0) at strip-loop bottom (no cross-strip
// load hoisting). W in LDS in fragment order; swapped MFMA; NT dwordx4 stores.
__global__ __launch_bounds__(1024, 4) void gemm_kernel(
    const float* __restrict__ x,
    const unsigned short* __restrict__ Wfrag,
    const float* __restrict__ bias,
    float* __restrict__ out, int nstrips, int spw) {
  __shared__ unsigned char lds[192 * 192 * 2];   // 73728 B, fragment order
  const int tid  = threadIdx.x;
  const int lane = tid & 63;
  const int wid  = tid >> 6;
  const int l15  = lane & 15;
  const int lhi  = lane >> 4;

  // Stage W fragments into LDS (linear copy; 4608 int4 / 1024 thr = 4.5 rounds).
  {
    const int4v* src = (const int4v*)Wfrag;
    int4v* dst = (int4v*)lds;
    #pragma unroll
    for (int t = 0; t < 5; ++t) {
      int idx = tid + t * 1024;
      if (idx < 4608) dst[idx] = src[idx];
    }
  }
  __syncthreads();

  const int gw = blockIdx.x * 16 + wid;    // global wave id
  int strip = gw * spw;
  const int send = min(strip + spw, nstrips);

  // bias for this lane's 4 output features (j = ct*16 + lhi*4 + r)
  const f32x4 bias4 = *(const f32x4*)(bias + lhi * 4);
  // LDS fragment base for this lane: frag (ct,c) at lane*16 + (ct*6+c)*1024
  const unsigned char* wbase = lds + lane * 16;

  while (strip < send) {
    short8 abf[6];
    {
      const float* xr = x + (size_t)(strip * 16 + l15) * 192 + lhi * 8;
      // Batch A: lo halves (k = c*32 + lhi*8 + 0..3)
      f32x4 fa[6];
      #pragma unroll
      for (int c = 0; c < 6; ++c) fa[c] = *(const f32x4*)(xr + c * 32);
      #pragma unroll
      for (int c = 0; c < 6; ++c)
        #pragma unroll
        for (int e = 0; e < 4; ++e) abf[c][e] = (short)f2bf(fa[c][e]);
      // Batch B: hi halves (k = c*32 + lhi*8 + 4..7)
      f32x4 fb[6];
      #pragma unroll
      for (int c = 0; c < 6; ++c) fb[c] = *(const f32x4*)(xr + c * 32 + 4);
      #pragma unroll
      for (int c = 0; c < 6; ++c)
        #pragma unroll
        for (int e = 0; e < 4; ++e) abf[c][e + 4] = (short)f2bf(fb[c][e]);
    }

    float* obase = out + (size_t)(strip * 16 + l15) * 192 + lhi * 4;
    #pragma unroll
    for (int ct = 0; ct < 12; ++ct) {
      f32x4 acc = {0.f, 0.f, 0.f, 0.f};
      #pragma unroll
      for (int c = 0; c < 6; ++c) {
        short8 w = *(const short8*)(wbase + (ct * 6 + c) * 1024);
        acc = __builtin_amdgcn_mfma_f32_16x16x32_bf16(w, abf[c], acc, 0, 0, 0);
      }
      f32x4 res = {acc[0] + bias4[0], acc[1] + bias4[1],
                   acc[2] + bias4[2], acc[3] + bias4[3]};
      __builtin_nontemporal_store(res, (f32x4*)(obase + ct * 16));
    }
    ++strip;
    // Fence: forbid hoisting next strip's loads above this point (spill source).
    __builtin_amdgcn_sched_barrier(0);
  }
}

extern "C" void kernel_launch(void* const* d_in, const int* in_sizes, int n_in,
                              void* d_out, int out_size, void* d_ws, size_t ws_size,
                              hipStream_t stream) {
    const float* x      = (const float*)d_in[0];
    const float* kern   = (const float*)d_in[1];
    const float* bias   = (const float*)d_in[2];
    const int*   cayley = (const int*)d_in[3];
    const int*   inv    = (const int*)d_in[4];
    float* out = (float*)d_out;
    unsigned short* Wfrag = (unsigned short*)d_ws;   // 73728 bytes

    const int nrows = in_sizes[0] / 192;
    const int nstrips = nrows / 16;                  // 32768

    build_w_kernel<<<(192 * 192 + 255) / 256, 256, 0, stream>>>(kern, cayley, inv, Wfrag);

    const int nblocks = 512;                         // persistent, 2 blocks/CU (32 waves/CU)
    const int nwaves  = nblocks * 16;                // 8192 waves
    const int spw     = (nstrips + nwaves - 1) / nwaves;   // = 4
    gemm_kernel<<<nblocks, 1024, 0, stream>>>(x, Wfrag, bias, out, nstrips, spw);
}

// Round 12
// 182.503 us; speedup vs baseline: 1.2081x; 1.2081x over previous
//
#include <hip/hip_runtime.h>
#include <hip/hip_bf16.h>
#include <stdint.h>

typedef __attribute__((ext_vector_type(8))) short short8;
typedef __attribute__((ext_vector_type(4))) float f32x4;
typedef __attribute__((ext_vector_type(4))) int int4v;

__device__ __forceinline__ unsigned short f2bf(float f) {
    union { float f; uint32_t u; } v; v.f = f;
    return (unsigned short)((v.u + 0x7FFFu + ((v.u >> 16) & 1u)) >> 16);
}

// Build W directly in MFMA-FRAGMENT order:
//   Wfrag[((ct*6 + c)*64 + lane)*8 + e] = bf16( W[ct*16 + (lane&15)][c*32 + (lane>>4)*8 + e] )
// where W[j][k] = kernel[cayley[inv[k>>4], j>>4]][j&15][k&15].
// Each wave's ds_read_b128 for (ct,c) is lane-linear 16B -> conflict-free (R8/R9: 0 conflicts).
__global__ void build_w_kernel(const float* __restrict__ kern,
                               const int* __restrict__ cayley,
                               const int* __restrict__ inv,
                               unsigned short* __restrict__ Wfrag) {
    int i = blockIdx.x * blockDim.x + threadIdx.x;   // i = ((ct*6+c)*64 + lane)*8 + e
    if (i >= 192 * 192) return;
    int e    = i & 7;
    int lane = (i >> 3) & 63;
    int fc   = i >> 9;            // ct*6 + c
    int ct   = fc / 6, c = fc - ct * 6;
    int j = ct * 16 + (lane & 15);
    int k = c * 32 + (lane >> 4) * 8 + e;
    int h = j >> 4, oc = j & 15;
    int g = k >> 4, ic = k & 15;
    int cidx = cayley[inv[g] * 12 + h];
    Wfrag[i] = f2bf(kern[cidx * 256 + oc * 16 + ic]);
}

// out[n][j] = sum_k x[n][k] * W[j][k] + bias[j]
// R10 post-mortem: perf flat across 11/32/43% occupancy -> NOT residency-bound.
// Theory: NT stores (64B segments: 4 lanes x 16B per line, adjacent 64B written
// by a different instruction) bypass L2 write-combining -> partial-128B-sector
// HBM bursts -> ~half write rate + ~1.2x WRITE_SIZE amplification (472-513 MB
// observed vs 402.7 ideal). This round, SINGLE variable vs R9 (best, 203.7us):
// plain stores (L2 allocates + combines 64B pairs into full sectors).
// Everything else identical to R9: 512-thr blocks, (512,4)=>64-VGPR cap (R9:
// VGPR=60, zero spills), two-batch staging, sched_barrier(0) at loop bottom,
// W in LDS in fragment order, swapped MFMA.
__global__ __launch_bounds__(512, 4) void gemm_kernel(
    const float* __restrict__ x,
    const unsigned short* __restrict__ Wfrag,
    const float* __restrict__ bias,
    float* __restrict__ out, int nstrips, int spw) {
  __shared__ unsigned char lds[192 * 192 * 2];   // 73728 B, fragment order
  const int tid  = threadIdx.x;
  const int lane = tid & 63;
  const int wid  = tid >> 6;
  const int l15  = lane & 15;
  const int lhi  = lane >> 4;

  // Stage W fragments into LDS (pure linear copy, 73728 B / 512 thr = 9 x int4).
  {
    const int4v* src = (const int4v*)Wfrag;
    int4v* dst = (int4v*)lds;
    #pragma unroll
    for (int t = 0; t < 9; ++t) dst[tid + t * 512] = src[tid + t * 512];
  }
  __syncthreads();

  const int gw = blockIdx.x * 8 + wid;    // global wave id
  int strip = gw * spw;
  const int send = min(strip + spw, nstrips);

  // bias for this lane's 4 output features (j = ct*16 + lhi*4 + r)
  const f32x4 bias4 = *(const f32x4*)(bias + lhi * 4);
  // LDS fragment base for this lane: frag (ct,c) at lane*16 + (ct*6+c)*1024
  const unsigned char* wbase = lds + lane * 16;

  while (strip < send) {
    short8 abf[6];
    {
      const float* xr = x + (size_t)(strip * 16 + l15) * 192 + lhi * 8;
      // Batch A: lo halves (k = c*32 + lhi*8 + 0..3)
      f32x4 fa[6];
      #pragma unroll
      for (int c = 0; c < 6; ++c) fa[c] = *(const f32x4*)(xr + c * 32);
      #pragma unroll
      for (int c = 0; c < 6; ++c)
        #pragma unroll
        for (int e = 0; e < 4; ++e) abf[c][e] = (short)f2bf(fa[c][e]);
      // Batch B: hi halves (k = c*32 + lhi*8 + 4..7)
      f32x4 fb[6];
      #pragma unroll
      for (int c = 0; c < 6; ++c) fb[c] = *(const f32x4*)(xr + c * 32 + 4);
      #pragma unroll
      for (int c = 0; c < 6; ++c)
        #pragma unroll
        for (int e = 0; e < 4; ++e) abf[c][e + 4] = (short)f2bf(fb[c][e]);
    }

    float* obase = out + (size_t)(strip * 16 + l15) * 192 + lhi * 4;
    #pragma unroll
    for (int ct = 0; ct < 12; ++ct) {
      f32x4 acc = {0.f, 0.f, 0.f, 0.f};
      #pragma unroll
      for (int c = 0; c < 6; ++c) {
        short8 w = *(const short8*)(wbase + (ct * 6 + c) * 1024);
        acc = __builtin_amdgcn_mfma_f32_16x16x32_bf16(w, abf[c], acc, 0, 0, 0);
      }
      f32x4 res = {acc[0] + bias4[0], acc[1] + bias4[1],
                   acc[2] + bias4[2], acc[3] + bias4[3]};
      *(f32x4*)(obase + ct * 16) = res;   // plain store: L2 write-combines sectors
    }
    ++strip;
    // Fence: forbid hoisting next strip's loads above this point (spill source).
    __builtin_amdgcn_sched_barrier(0);
  }
}

extern "C" void kernel_launch(void* const* d_in, const int* in_sizes, int n_in,
                              void* d_out, int out_size, void* d_ws, size_t ws_size,
                              hipStream_t stream) {
    const float* x      = (const float*)d_in[0];
    const float* kern   = (const float*)d_in[1];
    const float* bias   = (const float*)d_in[2];
    const int*   cayley = (const int*)d_in[3];
    const int*   inv    = (const int*)d_in[4];
    float* out = (float*)d_out;
    unsigned short* Wfrag = (unsigned short*)d_ws;   // 73728 bytes

    const int nrows = in_sizes[0] / 192;
    const int nstrips = nrows / 16;                  // 32768

    build_w_kernel<<<(192 * 192 + 255) / 256, 256, 0, stream>>>(kern, cayley, inv, Wfrag);

    const int nblocks = 512;                         // persistent, 2 blocks/CU
    const int nwaves  = nblocks * 8;                 // 4096 waves
    const int spw     = (nstrips + nwaves - 1) / nwaves;   // = 8
    gemm_kernel<<<nblocks, 512, 0, stream>>>(x, Wfrag, bias, out, nstrips, spw);
}